// Round 8
// baseline (852.201 us; speedup 1.0000x reference)
//
#include <hip/hip_runtime.h>

// ---------------------------------------------------------------------------
// SpGAT: x@W0+b0 -> 8x GAT heads (concat 512) -> GAT(512->64) -> softmax.
// R4: aggregate xp (256 B/edge, all 8 heads at once) then per-head GEMM.
// R5: owner-computes CSR build (per-XCD node ranges).
// R6: head scores via MFMA GEMM s16 = xp @ [was||wad]^T.
// R7: bf16 h2, CHUNK 20000.
// R8: agg_final lane-parallel weights + shfl broadcast (1 exp/edge, not 64);
//     agg_xp 8-edge unroll (16 outstanding gathers).
// ---------------------------------------------------------------------------

using bf16x8 = __bf16 __attribute__((ext_vector_type(8)));
using f32x4  = float  __attribute__((ext_vector_type(4)));

__device__ __forceinline__ unsigned short f2bf(float f) {
    __bf16 h = (__bf16)f;                       // fptrunc, RNE
    return __builtin_bit_cast(unsigned short, h);
}
__device__ __forceinline__ float bflo(unsigned int u) {
    return __builtin_bit_cast(float, u << 16);
}
__device__ __forceinline__ float bfhi(unsigned int u) {
    return __builtin_bit_cast(float, u & 0xffff0000u);
}
__device__ __forceinline__ float bfs(unsigned short u) {
    return __builtin_bit_cast(float, (unsigned)u << 16);
}

#define ALPHA_NEG 0.2f
#define CHUNK 20000

// ------------------------------ pack kernels -------------------------------
__global__ void pack_w0(const float* __restrict__ W0, unsigned short* __restrict__ W0t) {
    int idx = blockIdx.x * 256 + threadIdx.x;      // 16384
    int n = idx >> 7, k = idx & 127;
    W0t[n * 128 + k] = f2bf(W0[k * 128 + n]);
}
// W_heads [8][128k][64f] fp32 -> Ballt [h][f][k] bf16  (= per-head B^T)
__global__ void pack_ball(const float* __restrict__ Wh, unsigned short* __restrict__ Bt) {
    int idx = blockIdx.x * 256 + threadIdx.x;      // 65536
    int c = idx >> 7, k = idx & 127;
    int h = c >> 6, f = c & 63;
    Bt[idx] = f2bf(Wh[(h * 128 + k) * 64 + f]);
}
__global__ void pack_wend(const float* __restrict__ We, unsigned short* __restrict__ Bt) {
    int idx = blockIdx.x * 256 + threadIdx.x;      // 32768
    int n = idx >> 9, k = idx & 511;
    Bt[idx] = f2bf(We[k * 64 + n]);
}
// Bscore[16][128] bf16: row h = w~_src[h][k]; row 8+h = w~_dst[h][k]
__global__ void pack_wa(const float* __restrict__ Wh, const float* __restrict__ ah,
                        unsigned short* __restrict__ Bscore) {
    int idx = blockIdx.x * 256 + threadIdx.x;      // 1024
    if (idx >= 1024) return;
    int h = idx >> 7, k = idx & 127;
    float s = 0.f, d = 0.f;
    for (int f = 0; f < 64; f++) {
        float wv = Wh[(h * 128 + k) * 64 + f];
        s += wv * ah[h * 128 + f];
        d += wv * ah[h * 128 + 64 + f];
    }
    Bscore[h * 128 + k] = f2bf(s);
    Bscore[(8 + h) * 128 + k] = f2bf(d);
}

// ---------------------- CSR build (owner-computes per XCD) -----------------
__global__ void edge_hist_own(const int* __restrict__ src, int* __restrict__ deg,
                              int E, int npo) {
    int owner = blockIdx.x & 7;
    int i = (blockIdx.x >> 3) * 256 + threadIdx.x;
    if (i >= E) return;
    int s = src[i];
    int lo = owner * npo;
    if (s >= lo && s < lo + npo) atomicAdd(&deg[s], 1);
}
__global__ void edge_scatter_own(const int* __restrict__ src, const int* __restrict__ dst,
                                 int* __restrict__ cursor, int* __restrict__ dstp,
                                 int E, int npo) {
    int owner = blockIdx.x & 7;
    int i = (blockIdx.x >> 3) * 256 + threadIdx.x;
    if (i >= E) return;
    int s = src[i];
    int lo = owner * npo;
    if (s >= lo && s < lo + npo) {
        int p = atomicAdd(&cursor[s], 1);
        dstp[p] = dst[i];
    }
}

#define SCAN_BS 256
__global__ void scan_blocks(const int* __restrict__ deg, int* __restrict__ incl,
                            int* __restrict__ partials, int n) {
    __shared__ int s[SCAN_BS];
    int t = threadIdx.x, i = blockIdx.x * SCAN_BS + t;
    int v = (i < n) ? deg[i] : 0;
    s[t] = v; __syncthreads();
    for (int off = 1; off < SCAN_BS; off <<= 1) {
        int add = (t >= off) ? s[t - off] : 0;
        __syncthreads();
        s[t] += add;
        __syncthreads();
    }
    if (i < n) incl[i] = s[t];
    if (t == SCAN_BS - 1) partials[blockIdx.x] = s[t];
}
__global__ void scan_partials(int* __restrict__ partials, int nb) {  // 1 block, 512 thr
    __shared__ int s[512];
    int t = threadIdx.x;
    int v = (t < nb) ? partials[t] : 0;
    s[t] = v; __syncthreads();
    for (int off = 1; off < 512; off <<= 1) {
        int add = (t >= off) ? s[t - off] : 0;
        __syncthreads();
        s[t] += add;
        __syncthreads();
    }
    if (t < nb) partials[t] = s[t] - v;   // exclusive block offset
}
__global__ void finalize_rowptr(const int* __restrict__ deg, const int* __restrict__ incl,
                                const int* __restrict__ partials, int* __restrict__ row_ptr,
                                int* __restrict__ cursor, int n, int E) {
    int i = blockIdx.x * 256 + threadIdx.x;
    if (i < n) {
        int v = incl[i] - deg[i] + partials[i / SCAN_BS];
        row_ptr[i] = v;
        cursor[i] = v;
    } else if (i == n) {
        row_ptr[n] = E;
    }
}

// ------------------------------- MFMA GEMM ---------------------------------
template <int BM, int BN, int K, int WM, int WN, int MT, int NT,
          bool AF32, bool BIAS, bool OBF16, bool ELU, bool BATCHZ>
__launch_bounds__(256)
__global__ void gemm_mfma(const void* __restrict__ Ap, const unsigned short* __restrict__ Bt,
                          const float* __restrict__ bias, void* __restrict__ Cp, int M,
                          int lda, int ldc) {
    constexpr int LDK = 40;                    // pad 32 -> 40 shorts (80B rows, 16B-aligned)
    __shared__ unsigned short As[BM * LDK];
    __shared__ unsigned short Bs[BN * LDK];
    const int t = threadIdx.x;
    const long m0 = (long)blockIdx.x * BM;
    const long n0 = (long)blockIdx.y * BN;
    const int abase = BATCHZ ? blockIdx.z * K : 0;
    const unsigned short* Btz = BATCHZ ? Bt + (size_t)blockIdx.z * BN * K : Bt;
    const long cbase = BATCHZ ? (long)blockIdx.z * BN : 0;
    const int wave = t >> 6, lane = t & 63;
    const int wm = wave / WN, wn = wave % WN;
    const int lrow = lane & 15, lq = lane >> 4;

    f32x4 acc[MT][NT];
#pragma unroll
    for (int a = 0; a < MT; a++)
#pragma unroll
        for (int b = 0; b < NT; b++) acc[a][b] = (f32x4)0.0f;

    for (int kt = 0; kt < K / 32; kt++) {
        const int k0 = kt * 32;
        if constexpr (AF32) {
            const float* A = (const float*)Ap;
#pragma unroll
            for (int it = 0; it < BM * 8 / 256; it++) {
                int L = t + 256 * it;
                int row = L >> 3, kc = (L & 7) * 4;
                long gr = m0 + row;
                float4 v = make_float4(0.f, 0.f, 0.f, 0.f);
                if (gr < M) v = *(const float4*)&A[gr * lda + abase + k0 + kc];
                unsigned int lo = (unsigned)f2bf(v.x) | ((unsigned)f2bf(v.y) << 16);
                unsigned int hi = (unsigned)f2bf(v.z) | ((unsigned)f2bf(v.w) << 16);
                *(uint2*)&As[row * LDK + kc] = make_uint2(lo, hi);
            }
        } else {
            const unsigned short* A = (const unsigned short*)Ap;
#pragma unroll
            for (int it = 0; it < BM * 4 / 256; it++) {
                int L = t + 256 * it;
                int row = L >> 2, kc = (L & 3) * 8;
                long gr = m0 + row;
                uint4 v = make_uint4(0u, 0u, 0u, 0u);
                if (gr < M) v = *(const uint4*)&A[gr * lda + abase + k0 + kc];
                *(uint4*)&As[row * LDK + kc] = v;
            }
        }
#pragma unroll
        for (int it = 0; it < (BN * 4 + 255) / 256; it++) {
            int L = t + 256 * it;
            if (L < BN * 4) {
                int row = L >> 2, kc = (L & 3) * 8;
                *(uint4*)&Bs[row * LDK + kc] = *(const uint4*)&Btz[(n0 + row) * K + k0 + kc];
            }
        }
        __syncthreads();

        bf16x8 af[MT], bfr[NT];
#pragma unroll
        for (int mt = 0; mt < MT; mt++)
            af[mt] = *(const bf16x8*)&As[((wm * MT + mt) * 16 + lrow) * LDK + lq * 8];
#pragma unroll
        for (int nt = 0; nt < NT; nt++)
            bfr[nt] = *(const bf16x8*)&Bs[((wn * NT + nt) * 16 + lrow) * LDK + lq * 8];
#pragma unroll
        for (int mt = 0; mt < MT; mt++)
#pragma unroll
            for (int nt = 0; nt < NT; nt++)
                acc[mt][nt] = __builtin_amdgcn_mfma_f32_16x16x32_bf16(af[mt], bfr[nt],
                                                                     acc[mt][nt], 0, 0, 0);
        __syncthreads();
    }

#pragma unroll
    for (int mt = 0; mt < MT; mt++) {
        long rbase = m0 + (wm * MT + mt) * 16 + lq * 4;
#pragma unroll
        for (int nt = 0; nt < NT; nt++) {
            long col = cbase + n0 + (wn * NT + nt) * 16 + lrow;
            float bv = 0.f;
            if constexpr (BIAS) bv = bias[col];
#pragma unroll
            for (int r = 0; r < 4; r++) {
                long row = rbase + r;
                if (row < M) {
                    float v = acc[mt][nt][r] + bv;
                    if constexpr (ELU) v = v > 0.f ? v : __expf(v) - 1.0f;
                    if constexpr (OBF16)
                        ((unsigned short*)Cp)[row * ldc + col] = f2bf(v);
                    else
                        ((float*)Cp)[row * ldc + col] = v;
                }
            }
        }
    }
}

// ---------------- 8-head xp aggregation (chunked), zero shuffles -----------
// Wave per node. lane: head h=lane>>3, sub=lane&7 -> owns xp cols sub*16..+15.
// 8/4/1 unroll ladder (R8): up to 16 outstanding uint4 gathers.
__global__ void agg_xp(const int* __restrict__ row_ptr, const int* __restrict__ dstp,
                       const float* __restrict__ s16,
                       const unsigned short* __restrict__ xp, unsigned short* __restrict__ z,
                       int n0, int n1) {
    int t = threadIdx.x, wave = t >> 6, lane = t & 63;
    int i = n0 + blockIdx.x * 4 + wave;
    if (i >= n1) return;
    int e0 = row_ptr[i], e1 = row_ptr[i + 1];
    int h = lane >> 3, sub = lane & 7;
    float ssv = s16[(size_t)i * 16 + h];
    float acc[16];
#pragma unroll
    for (int c = 0; c < 16; c++) acc[c] = 0.f;
    float rs = 0.f;
    int p = e0;
    for (; p + 8 <= e1; p += 8) {
        int j[8];
        float sc[8];
        uint4 xa[8], xb[8];
#pragma unroll
        for (int u = 0; u < 8; u++) j[u] = dstp[p + u];
#pragma unroll
        for (int u = 0; u < 8; u++) {
            sc[u] = ssv + s16[(size_t)j[u] * 16 + 8 + h];
            xa[u] = *(const uint4*)&xp[(size_t)j[u] * 128 + sub * 16];
            xb[u] = *(const uint4*)&xp[(size_t)j[u] * 128 + sub * 16 + 8];
        }
#pragma unroll
        for (int u = 0; u < 8; u++) {
            float s = sc[u];
            s = s > 0.f ? s : ALPHA_NEG * s;
            float w = __expf(-s);
            rs += w;
            unsigned ua[4] = {xa[u].x, xa[u].y, xa[u].z, xa[u].w};
            unsigned ub[4] = {xb[u].x, xb[u].y, xb[u].z, xb[u].w};
#pragma unroll
            for (int q = 0; q < 4; q++) {
                acc[2 * q]         += w * bflo(ua[q]);
                acc[2 * q + 1]     += w * bfhi(ua[q]);
                acc[8 + 2 * q]     += w * bflo(ub[q]);
                acc[8 + 2 * q + 1] += w * bfhi(ub[q]);
            }
        }
    }
    for (; p + 4 <= e1; p += 4) {
        int j[4];
        float sc[4];
        uint4 xa[4], xb[4];
#pragma unroll
        for (int u = 0; u < 4; u++) j[u] = dstp[p + u];
#pragma unroll
        for (int u = 0; u < 4; u++) {
            sc[u] = ssv + s16[(size_t)j[u] * 16 + 8 + h];
            xa[u] = *(const uint4*)&xp[(size_t)j[u] * 128 + sub * 16];
            xb[u] = *(const uint4*)&xp[(size_t)j[u] * 128 + sub * 16 + 8];
        }
#pragma unroll
        for (int u = 0; u < 4; u++) {
            float s = sc[u];
            s = s > 0.f ? s : ALPHA_NEG * s;
            float w = __expf(-s);
            rs += w;
            unsigned ua[4] = {xa[u].x, xa[u].y, xa[u].z, xa[u].w};
            unsigned ub[4] = {xb[u].x, xb[u].y, xb[u].z, xb[u].w};
#pragma unroll
            for (int q = 0; q < 4; q++) {
                acc[2 * q]         += w * bflo(ua[q]);
                acc[2 * q + 1]     += w * bfhi(ua[q]);
                acc[8 + 2 * q]     += w * bflo(ub[q]);
                acc[8 + 2 * q + 1] += w * bfhi(ub[q]);
            }
        }
    }
    for (; p < e1; p++) {
        int j0 = dstp[p];
        float s0 = ssv + s16[(size_t)j0 * 16 + 8 + h];
        uint4 xa0 = *(const uint4*)&xp[(size_t)j0 * 128 + sub * 16];
        uint4 xb0 = *(const uint4*)&xp[(size_t)j0 * 128 + sub * 16 + 8];
        s0 = s0 > 0.f ? s0 : ALPHA_NEG * s0;
        float w0 = __expf(-s0);
        rs += w0;
        unsigned ua0[4] = {xa0.x, xa0.y, xa0.z, xa0.w};
        unsigned ub0[4] = {xb0.x, xb0.y, xb0.z, xb0.w};
#pragma unroll
        for (int q = 0; q < 4; q++) {
            acc[2 * q]         += w0 * bflo(ua0[q]);
            acc[2 * q + 1]     += w0 * bfhi(ua0[q]);
            acc[8 + 2 * q]     += w0 * bflo(ub0[q]);
            acc[8 + 2 * q + 1] += w0 * bfhi(ub0[q]);
        }
    }
    float inv = 1.0f / (rs + 1e-16f);
    uint4 o0, o1;
    unsigned* po0 = (unsigned*)&o0;
    unsigned* po1 = (unsigned*)&o1;
#pragma unroll
    for (int q = 0; q < 4; q++) {
        po0[q] = (unsigned)f2bf(acc[2 * q] * inv) | ((unsigned)f2bf(acc[2 * q + 1] * inv) << 16);
        po1[q] = (unsigned)f2bf(acc[8 + 2 * q] * inv) | ((unsigned)f2bf(acc[8 + 2 * q + 1] * inv) << 16);
    }
    size_t zb = (size_t)(i - n0) * 1024 + h * 128 + sub * 16;
    *(uint4*)&z[zb] = o0;
    *(uint4*)&z[zb + 8] = o1;
}

// ----------------------------- final-layer scores --------------------------
__global__ void scores2(const unsigned short* __restrict__ h2b, const float* __restrict__ ae,
                        float* __restrict__ ss2, float* __restrict__ sd2, int n) {
    int t = threadIdx.x, wave = t >> 6, lane = t & 63;
    int i = blockIdx.x * 4 + wave;
    if (i >= n) return;
    float v = bfs(h2b[(size_t)i * 64 + lane]);
    float a = v * ae[lane];
    float b = v * ae[64 + lane];
    for (int d = 32; d > 0; d >>= 1) {
        a += __shfl_xor(a, d, 64);
        b += __shfl_xor(b, d, 64);
    }
    if (lane == 0) { ss2[i] = a; sd2[i] = b; }
}

// --------------------- final aggregation + row softmax ---------------------
// Wave per node. Edge chunk of 64: lane L computes weight for edge base+L
// (ONE exp per edge, coalesced dstp), rowsum via one butterfly per chunk,
// then shfl-broadcast (w,j) and 1 load + 1 FMA per lane per edge.  (R8)
__global__ void agg_final(const int* __restrict__ row_ptr, const int* __restrict__ dstp,
                          const float* __restrict__ ss2, const float* __restrict__ sd2,
                          const unsigned short* __restrict__ h2b, float* __restrict__ out,
                          int n) {
    int t = threadIdx.x, wave = t >> 6, lane = t & 63;
    int i = blockIdx.x * 4 + wave;
    if (i >= n) return;
    int e0 = row_ptr[i], e1 = row_ptr[i + 1];
    float ssrc = ss2[i];
    float acc = 0.f, rs = 0.f;
    for (int base = e0; base < e1; base += 64) {
        int cnt = e1 - base; if (cnt > 64) cnt = 64;
        int jv = 0; float wv = 0.f;
        if (lane < cnt) {
            jv = dstp[base + lane];
            float sc = ssrc + sd2[jv];
            sc = sc > 0.f ? sc : ALPHA_NEG * sc;
            wv = __expf(-sc);
        }
        float wsum = wv;
        for (int d = 32; d > 0; d >>= 1) wsum += __shfl_xor(wsum, d, 64);
        rs += wsum;
        int q = 0;
        for (; q + 4 <= cnt; q += 4) {
            float w0 = __shfl(wv, q),     w1 = __shfl(wv, q + 1);
            float w2 = __shfl(wv, q + 2), w3 = __shfl(wv, q + 3);
            int j0 = __shfl(jv, q),     j1 = __shfl(jv, q + 1);
            int j2 = __shfl(jv, q + 2), j3 = __shfl(jv, q + 3);
            float v0 = bfs(h2b[(size_t)j0 * 64 + lane]);
            float v1 = bfs(h2b[(size_t)j1 * 64 + lane]);
            float v2 = bfs(h2b[(size_t)j2 * 64 + lane]);
            float v3 = bfs(h2b[(size_t)j3 * 64 + lane]);
            acc += w0 * v0 + w1 * v1 + w2 * v2 + w3 * v3;
        }
        for (; q < cnt; q++) {
            float w = __shfl(wv, q);
            int j = __shfl(jv, q);
            acc += w * bfs(h2b[(size_t)j * 64 + lane]);
        }
    }
    float o = acc / (rs + 1e-16f);
    float m = o;
    for (int d = 32; d > 0; d >>= 1) m = fmaxf(m, __shfl_xor(m, d, 64));
    float e = __expf(o - m);
    float s = e;
    for (int d = 32; d > 0; d >>= 1) s += __shfl_xor(s, d, 64);
    out[(size_t)i * 64 + lane] = e / s;
}

// ------------------------------- launcher ----------------------------------
extern "C" void kernel_launch(void* const* d_in, const int* in_sizes, int n_in,
                              void* d_out, int out_size, void* d_ws, size_t ws_size,
                              hipStream_t stream) {
    const float* x  = (const float*)d_in[0];
    const int* edges = (const int*)d_in[1];
    const float* W0 = (const float*)d_in[2];
    const float* b0 = (const float*)d_in[3];
    const float* Wh = (const float*)d_in[4];
    const float* ah = (const float*)d_in[5];
    const float* We = (const float*)d_in[6];
    const float* ae = (const float*)d_in[7];
    float* dout = (float*)d_out;

    const int Nn = in_sizes[0] / 128;   // 100000
    const int E  = in_sizes[1] / 2;     // 1600000
    const int* src = edges;
    const int* dst = edges + E;
    const int npo = (Nn + 7) / 8;       // nodes per XCD owner

    char* p = (char*)d_ws;
    auto alloc = [&](size_t bytes) -> char* {
        char* r = p;
        p += (bytes + 255) & ~(size_t)255;
        return r;
    };
    unsigned short* W0t   = (unsigned short*)alloc(128 * 128 * 2);
    unsigned short* Ballt = (unsigned short*)alloc(512 * 128 * 2);
    unsigned short* Wendt = (unsigned short*)alloc((size_t)64 * 512 * 2);
    unsigned short* Bscore = (unsigned short*)alloc(16 * 128 * 2);
    int* deg     = (int*)alloc((size_t)Nn * 4);
    int* incl    = (int*)alloc((size_t)Nn * 4);
    int* part    = (int*)alloc(512 * 4);
    int* row_ptr = (int*)alloc((size_t)(Nn + 1) * 4);
    int* cursor  = (int*)alloc((size_t)Nn * 4);
    int* dstp    = (int*)alloc((size_t)E * 4);
    float* s16   = (float*)alloc((size_t)Nn * 16 * 4);
    float* ss2   = (float*)alloc((size_t)Nn * 4);
    float* sd2   = (float*)alloc((size_t)Nn * 4);
    unsigned short* xp = (unsigned short*)alloc((size_t)Nn * 128 * 2);
    unsigned short* z  = (unsigned short*)alloc((size_t)CHUNK * 1024 * 2); // h2b aliases
    unsigned short* hcat = (unsigned short*)alloc((size_t)Nn * 512 * 2);
    unsigned short* h2b = (unsigned short*)z;   // [N,64] bf16 = 12.8 MB << z

    size_t needed = (size_t)(p - (char*)d_ws);
    if (needed > ws_size) return;       // diagnostic guard

    const int gm = (Nn + 127) / 128;
    const int nScanB = (Nn + SCAN_BS - 1) / SCAN_BS;
    const int eb = (E + 255) / 256;     // edge chunks

    hipMemsetAsync(deg, 0, (size_t)Nn * 4, stream);
    pack_w0<<<64, 256, 0, stream>>>(W0, W0t);
    pack_ball<<<256, 256, 0, stream>>>(Wh, Ballt);
    pack_wend<<<128, 256, 0, stream>>>(We, Wendt);
    pack_wa<<<4, 256, 0, stream>>>(Wh, ah, Bscore);

    edge_hist_own<<<eb * 8, 256, 0, stream>>>(src, deg, E, npo);
    scan_blocks<<<nScanB, 256, 0, stream>>>(deg, incl, part, Nn);
    scan_partials<<<1, 512, 0, stream>>>(part, nScanB);
    finalize_rowptr<<<(Nn + 256) / 256, 256, 0, stream>>>(deg, incl, part, row_ptr, cursor, Nn, E);
    edge_scatter_own<<<eb * 8, 256, 0, stream>>>(src, dst, cursor, dstp, E, npo);

    // xp = bf16(x @ W0 + b0)
    gemm_mfma<128, 128, 128, 2, 2, 4, 4, true, true, true, false, false>
        <<<dim3(gm, 1), 256, 0, stream>>>(x, W0t, b0, xp, Nn, 128, 128);

    // s16[N,16] = xp @ Bscore^T  (cols 0..7 = src scores, 8..15 = dst scores)
    gemm_mfma<128, 16, 128, 4, 1, 2, 1, false, false, false, false, false>
        <<<dim3(gm, 1), 256, 0, stream>>>(xp, Bscore, nullptr, s16, Nn, 128, 16);

    // chunked: z = normalized xp-aggregation; hcat = ELU(z_h @ W_h) per head
    for (int c0 = 0; c0 < Nn; c0 += CHUNK) {
        int c1 = min(c0 + CHUNK, Nn);
        int Mc = c1 - c0;
        agg_xp<<<(Mc + 3) / 4, 256, 0, stream>>>(row_ptr, dstp, s16, xp, z, c0, c1);
        gemm_mfma<128, 64, 128, 4, 1, 2, 4, false, false, true, true, true>
            <<<dim3((Mc + 127) / 128, 1, 8), 256, 0, stream>>>(
                z, Ballt, nullptr, hcat + (size_t)c0 * 512, Mc, 1024, 512);
    }

    // h2b = bf16(hcat @ W_end)  [N,64]   (aliases z, now dead)
    gemm_mfma<128, 64, 512, 4, 1, 2, 4, false, false, true, false, false>
        <<<dim3(gm, 1), 256, 0, stream>>>(hcat, Wendt, nullptr, h2b, Nn, 512, 64);

    scores2<<<(Nn + 3) / 4, 256, 0, stream>>>(h2b, ae, ss2, sd2, Nn);
    agg_final<<<(Nn + 3) / 4, 256, 0, stream>>>(row_ptr, dstp, ss2, sd2, h2b, dout, Nn);
}

// Round 9
// 685.074 us; speedup vs baseline: 1.2440x; 1.2440x over previous
//
#include <hip/hip_runtime.h>

// ---------------------------------------------------------------------------
// SpGAT: x@W0+b0 -> 8x GAT heads (concat 512) -> GAT(512->64) -> softmax.
// R4: aggregate xp (256 B/edge, all 8 heads at once) then per-head GEMM.
// R5: owner-computes CSR build (per-XCD node ranges).
// R6: head scores via MFMA GEMM s16 = xp @ [was||wad]^T.
// R7: bf16 h2, CHUNK 20000.
// R8 kept: agg_final lane-parallel weights + shfl broadcast (1 exp/edge).
// R9: agg_xp reverted to 4-edge unroll and split 2-waves-per-node (4 heads
//     each): VGPR ~45 (was 64), 2x waves for latency hiding, 1 uint4/edge.
// ---------------------------------------------------------------------------

using bf16x8 = __bf16 __attribute__((ext_vector_type(8)));
using f32x4  = float  __attribute__((ext_vector_type(4)));

__device__ __forceinline__ unsigned short f2bf(float f) {
    __bf16 h = (__bf16)f;                       // fptrunc, RNE
    return __builtin_bit_cast(unsigned short, h);
}
__device__ __forceinline__ float bflo(unsigned int u) {
    return __builtin_bit_cast(float, u << 16);
}
__device__ __forceinline__ float bfhi(unsigned int u) {
    return __builtin_bit_cast(float, u & 0xffff0000u);
}
__device__ __forceinline__ float bfs(unsigned short u) {
    return __builtin_bit_cast(float, (unsigned)u << 16);
}

#define ALPHA_NEG 0.2f
#define CHUNK 20000

// --------------------------- merged pack kernel ----------------------------
// blocks 0..63: W0t; 64..319: Ballt; 320..447: Wendt; 448..451: Bscore
__global__ void pack_all(const float* __restrict__ W0, const float* __restrict__ Wh,
                         const float* __restrict__ We, const float* __restrict__ ah,
                         unsigned short* __restrict__ W0t, unsigned short* __restrict__ Ballt,
                         unsigned short* __restrict__ Wendt, unsigned short* __restrict__ Bscore) {
    int b = blockIdx.x, t = threadIdx.x;
    if (b < 64) {                               // W0 [128k][128n] -> [n][k]
        int idx = b * 256 + t;
        int n = idx >> 7, k = idx & 127;
        W0t[n * 128 + k] = f2bf(W0[k * 128 + n]);
    } else if (b < 320) {                       // Wh [8][128k][64f] -> [(h*64+f)][k]
        int idx = (b - 64) * 256 + t;
        int c = idx >> 7, k = idx & 127;
        int h = c >> 6, f = c & 63;
        Ballt[idx] = f2bf(Wh[(h * 128 + k) * 64 + f]);
    } else if (b < 448) {                       // We [512k][64n] -> [n][k]
        int idx = (b - 320) * 256 + t;
        int n = idx >> 9, k = idx & 511;
        Wendt[idx] = f2bf(We[k * 64 + n]);
    } else {                                    // Bscore [16][128]
        int idx = (b - 448) * 256 + t;
        if (idx < 1024) {
            int h = idx >> 7, k = idx & 127;
            float s = 0.f, d = 0.f;
            for (int f = 0; f < 64; f++) {
                float wv = Wh[(h * 128 + k) * 64 + f];
                s += wv * ah[h * 128 + f];
                d += wv * ah[h * 128 + 64 + f];
            }
            Bscore[h * 128 + k] = f2bf(s);
            Bscore[(8 + h) * 128 + k] = f2bf(d);
        }
    }
}

// ---------------------- CSR build (owner-computes per XCD) -----------------
__global__ void edge_hist_own(const int* __restrict__ src, int* __restrict__ deg,
                              int E, int npo) {
    int owner = blockIdx.x & 7;
    int i = (blockIdx.x >> 3) * 256 + threadIdx.x;
    if (i >= E) return;
    int s = src[i];
    int lo = owner * npo;
    if (s >= lo && s < lo + npo) atomicAdd(&deg[s], 1);
}
__global__ void edge_scatter_own(const int* __restrict__ src, const int* __restrict__ dst,
                                 int* __restrict__ cursor, int* __restrict__ dstp,
                                 int E, int npo) {
    int owner = blockIdx.x & 7;
    int i = (blockIdx.x >> 3) * 256 + threadIdx.x;
    if (i >= E) return;
    int s = src[i];
    int lo = owner * npo;
    if (s >= lo && s < lo + npo) {
        int p = atomicAdd(&cursor[s], 1);
        dstp[p] = dst[i];
    }
}

#define SCAN_BS 256
__global__ void scan_blocks(const int* __restrict__ deg, int* __restrict__ incl,
                            int* __restrict__ partials, int n) {
    __shared__ int s[SCAN_BS];
    int t = threadIdx.x, i = blockIdx.x * SCAN_BS + t;
    int v = (i < n) ? deg[i] : 0;
    s[t] = v; __syncthreads();
    for (int off = 1; off < SCAN_BS; off <<= 1) {
        int add = (t >= off) ? s[t - off] : 0;
        __syncthreads();
        s[t] += add;
        __syncthreads();
    }
    if (i < n) incl[i] = s[t];
    if (t == SCAN_BS - 1) partials[blockIdx.x] = s[t];
}
__global__ void scan_partials(int* __restrict__ partials, int nb) {  // 1 block, 512 thr
    __shared__ int s[512];
    int t = threadIdx.x;
    int v = (t < nb) ? partials[t] : 0;
    s[t] = v; __syncthreads();
    for (int off = 1; off < 512; off <<= 1) {
        int add = (t >= off) ? s[t - off] : 0;
        __syncthreads();
        s[t] += add;
        __syncthreads();
    }
    if (t < nb) partials[t] = s[t] - v;   // exclusive block offset
}
__global__ void finalize_rowptr(const int* __restrict__ deg, const int* __restrict__ incl,
                                const int* __restrict__ partials, int* __restrict__ row_ptr,
                                int* __restrict__ cursor, int n, int E) {
    int i = blockIdx.x * 256 + threadIdx.x;
    if (i < n) {
        int v = incl[i] - deg[i] + partials[i / SCAN_BS];
        row_ptr[i] = v;
        cursor[i] = v;
    } else if (i == n) {
        row_ptr[n] = E;
    }
}

// ------------------------------- MFMA GEMM ---------------------------------
template <int BM, int BN, int K, int WM, int WN, int MT, int NT,
          bool AF32, bool BIAS, bool OBF16, bool ELU, bool BATCHZ>
__launch_bounds__(256)
__global__ void gemm_mfma(const void* __restrict__ Ap, const unsigned short* __restrict__ Bt,
                          const float* __restrict__ bias, void* __restrict__ Cp, int M,
                          int lda, int ldc) {
    constexpr int LDK = 40;                    // pad 32 -> 40 shorts (80B rows, 16B-aligned)
    __shared__ unsigned short As[BM * LDK];
    __shared__ unsigned short Bs[BN * LDK];
    const int t = threadIdx.x;
    const long m0 = (long)blockIdx.x * BM;
    const long n0 = (long)blockIdx.y * BN;
    const int abase = BATCHZ ? blockIdx.z * K : 0;
    const unsigned short* Btz = BATCHZ ? Bt + (size_t)blockIdx.z * BN * K : Bt;
    const long cbase = BATCHZ ? (long)blockIdx.z * BN : 0;
    const int wave = t >> 6, lane = t & 63;
    const int wm = wave / WN, wn = wave % WN;
    const int lrow = lane & 15, lq = lane >> 4;

    f32x4 acc[MT][NT];
#pragma unroll
    for (int a = 0; a < MT; a++)
#pragma unroll
        for (int b = 0; b < NT; b++) acc[a][b] = (f32x4)0.0f;

    for (int kt = 0; kt < K / 32; kt++) {
        const int k0 = kt * 32;
        if constexpr (AF32) {
            const float* A = (const float*)Ap;
#pragma unroll
            for (int it = 0; it < BM * 8 / 256; it++) {
                int L = t + 256 * it;
                int row = L >> 3, kc = (L & 7) * 4;
                long gr = m0 + row;
                float4 v = make_float4(0.f, 0.f, 0.f, 0.f);
                if (gr < M) v = *(const float4*)&A[gr * lda + abase + k0 + kc];
                unsigned int lo = (unsigned)f2bf(v.x) | ((unsigned)f2bf(v.y) << 16);
                unsigned int hi = (unsigned)f2bf(v.z) | ((unsigned)f2bf(v.w) << 16);
                *(uint2*)&As[row * LDK + kc] = make_uint2(lo, hi);
            }
        } else {
            const unsigned short* A = (const unsigned short*)Ap;
#pragma unroll
            for (int it = 0; it < BM * 4 / 256; it++) {
                int L = t + 256 * it;
                int row = L >> 2, kc = (L & 3) * 8;
                long gr = m0 + row;
                uint4 v = make_uint4(0u, 0u, 0u, 0u);
                if (gr < M) v = *(const uint4*)&A[gr * lda + abase + k0 + kc];
                *(uint4*)&As[row * LDK + kc] = v;
            }
        }
#pragma unroll
        for (int it = 0; it < (BN * 4 + 255) / 256; it++) {
            int L = t + 256 * it;
            if (L < BN * 4) {
                int row = L >> 2, kc = (L & 3) * 8;
                *(uint4*)&Bs[row * LDK + kc] = *(const uint4*)&Btz[(n0 + row) * K + k0 + kc];
            }
        }
        __syncthreads();

        bf16x8 af[MT], bfr[NT];
#pragma unroll
        for (int mt = 0; mt < MT; mt++)
            af[mt] = *(const bf16x8*)&As[((wm * MT + mt) * 16 + lrow) * LDK + lq * 8];
#pragma unroll
        for (int nt = 0; nt < NT; nt++)
            bfr[nt] = *(const bf16x8*)&Bs[((wn * NT + nt) * 16 + lrow) * LDK + lq * 8];
#pragma unroll
        for (int mt = 0; mt < MT; mt++)
#pragma unroll
            for (int nt = 0; nt < NT; nt++)
                acc[mt][nt] = __builtin_amdgcn_mfma_f32_16x16x32_bf16(af[mt], bfr[nt],
                                                                     acc[mt][nt], 0, 0, 0);
        __syncthreads();
    }

#pragma unroll
    for (int mt = 0; mt < MT; mt++) {
        long rbase = m0 + (wm * MT + mt) * 16 + lq * 4;
#pragma unroll
        for (int nt = 0; nt < NT; nt++) {
            long col = cbase + n0 + (wn * NT + nt) * 16 + lrow;
            float bv = 0.f;
            if constexpr (BIAS) bv = bias[col];
#pragma unroll
            for (int r = 0; r < 4; r++) {
                long row = rbase + r;
                if (row < M) {
                    float v = acc[mt][nt][r] + bv;
                    if constexpr (ELU) v = v > 0.f ? v : __expf(v) - 1.0f;
                    if constexpr (OBF16)
                        ((unsigned short*)Cp)[row * ldc + col] = f2bf(v);
                    else
                        ((float*)Cp)[row * ldc + col] = v;
                }
            }
        }
    }
}

// ---------------- 8-head xp aggregation: 2 waves per node (R9) -------------
// Block = 256 thr = 2 nodes x 2 waves. Wave handles 4 heads:
// h = (wave&1)*4 + (lane>>4), sub = lane&15 -> owns xp cols sub*8..+7.
// Per edge: ONE uint4 gather per lane; 8 acc FMAs. 4-edge unroll.
__global__ void agg_xp(const int* __restrict__ row_ptr, const int* __restrict__ dstp,
                       const float* __restrict__ s16,
                       const unsigned short* __restrict__ xp, unsigned short* __restrict__ z,
                       int n0, int n1) {
    int t = threadIdx.x, wave = t >> 6, lane = t & 63;
    int i = n0 + blockIdx.x * 2 + (wave >> 1);
    if (i >= n1) return;
    int e0 = row_ptr[i], e1 = row_ptr[i + 1];
    int h = (wave & 1) * 4 + (lane >> 4), sub = lane & 15;
    float ssv = s16[(size_t)i * 16 + h];
    float acc[8];
#pragma unroll
    for (int c = 0; c < 8; c++) acc[c] = 0.f;
    float rs = 0.f;
    int p = e0;
    for (; p + 4 <= e1; p += 4) {
        int j[4];
        float sc[4];
        uint4 xa[4];
#pragma unroll
        for (int u = 0; u < 4; u++) j[u] = dstp[p + u];
#pragma unroll
        for (int u = 0; u < 4; u++) {
            sc[u] = s16[(size_t)j[u] * 16 + 8 + h];
            xa[u] = *(const uint4*)&xp[(size_t)j[u] * 128 + sub * 8];
        }
#pragma unroll
        for (int u = 0; u < 4; u++) {
            float s = ssv + sc[u];
            s = s > 0.f ? s : ALPHA_NEG * s;
            float w = __expf(-s);
            rs += w;
            unsigned ua[4] = {xa[u].x, xa[u].y, xa[u].z, xa[u].w};
#pragma unroll
            for (int q = 0; q < 4; q++) {
                acc[2 * q]     += w * bflo(ua[q]);
                acc[2 * q + 1] += w * bfhi(ua[q]);
            }
        }
    }
    for (; p < e1; p++) {
        int j0 = dstp[p];
        float s0 = ssv + s16[(size_t)j0 * 16 + 8 + h];
        uint4 xa0 = *(const uint4*)&xp[(size_t)j0 * 128 + sub * 8];
        s0 = s0 > 0.f ? s0 : ALPHA_NEG * s0;
        float w0 = __expf(-s0);
        rs += w0;
        unsigned ua0[4] = {xa0.x, xa0.y, xa0.z, xa0.w};
#pragma unroll
        for (int q = 0; q < 4; q++) {
            acc[2 * q]     += w0 * bflo(ua0[q]);
            acc[2 * q + 1] += w0 * bfhi(ua0[q]);
        }
    }
    float inv = 1.0f / (rs + 1e-16f);
    uint4 o;
    unsigned* po = (unsigned*)&o;
#pragma unroll
    for (int q = 0; q < 4; q++)
        po[q] = (unsigned)f2bf(acc[2 * q] * inv) | ((unsigned)f2bf(acc[2 * q + 1] * inv) << 16);
    *(uint4*)&z[(size_t)(i - n0) * 1024 + h * 128 + sub * 8] = o;
}

// ----------------------------- final-layer scores --------------------------
__global__ void scores2(const unsigned short* __restrict__ h2b, const float* __restrict__ ae,
                        float* __restrict__ ss2, float* __restrict__ sd2, int n) {
    int t = threadIdx.x, wave = t >> 6, lane = t & 63;
    int i = blockIdx.x * 4 + wave;
    if (i >= n) return;
    float v = bfs(h2b[(size_t)i * 64 + lane]);
    float a = v * ae[lane];
    float b = v * ae[64 + lane];
    for (int d = 32; d > 0; d >>= 1) {
        a += __shfl_xor(a, d, 64);
        b += __shfl_xor(b, d, 64);
    }
    if (lane == 0) { ss2[i] = a; sd2[i] = b; }
}

// --------------------- final aggregation + row softmax ---------------------
// Wave per node. Edge chunk of 64: lane L computes weight for edge base+L
// (one exp per edge, coalesced dstp), rowsum butterfly once per chunk,
// then shfl-broadcast (w,j): 1 load + 1 FMA per lane per edge.  (R8)
__global__ void agg_final(const int* __restrict__ row_ptr, const int* __restrict__ dstp,
                          const float* __restrict__ ss2, const float* __restrict__ sd2,
                          const unsigned short* __restrict__ h2b, float* __restrict__ out,
                          int n) {
    int t = threadIdx.x, wave = t >> 6, lane = t & 63;
    int i = blockIdx.x * 4 + wave;
    if (i >= n) return;
    int e0 = row_ptr[i], e1 = row_ptr[i + 1];
    float ssrc = ss2[i];
    float acc = 0.f, rs = 0.f;
    for (int base = e0; base < e1; base += 64) {
        int cnt = e1 - base; if (cnt > 64) cnt = 64;
        int jv = 0; float wv = 0.f;
        if (lane < cnt) {
            jv = dstp[base + lane];
            float sc = ssrc + sd2[jv];
            sc = sc > 0.f ? sc : ALPHA_NEG * sc;
            wv = __expf(-sc);
        }
        float wsum = wv;
        for (int d = 32; d > 0; d >>= 1) wsum += __shfl_xor(wsum, d, 64);
        rs += wsum;
        int q = 0;
        for (; q + 4 <= cnt; q += 4) {
            float w0 = __shfl(wv, q),     w1 = __shfl(wv, q + 1);
            float w2 = __shfl(wv, q + 2), w3 = __shfl(wv, q + 3);
            int j0 = __shfl(jv, q),     j1 = __shfl(jv, q + 1);
            int j2 = __shfl(jv, q + 2), j3 = __shfl(jv, q + 3);
            float v0 = bfs(h2b[(size_t)j0 * 64 + lane]);
            float v1 = bfs(h2b[(size_t)j1 * 64 + lane]);
            float v2 = bfs(h2b[(size_t)j2 * 64 + lane]);
            float v3 = bfs(h2b[(size_t)j3 * 64 + lane]);
            acc += w0 * v0 + w1 * v1 + w2 * v2 + w3 * v3;
        }
        for (; q < cnt; q++) {
            float w = __shfl(wv, q);
            int j = __shfl(jv, q);
            acc += w * bfs(h2b[(size_t)j * 64 + lane]);
        }
    }
    float o = acc / (rs + 1e-16f);
    float m = o;
    for (int d = 32; d > 0; d >>= 1) m = fmaxf(m, __shfl_xor(m, d, 64));
    float e = __expf(o - m);
    float s = e;
    for (int d = 32; d > 0; d >>= 1) s += __shfl_xor(s, d, 64);
    out[(size_t)i * 64 + lane] = e / s;
}

// ------------------------------- launcher ----------------------------------
extern "C" void kernel_launch(void* const* d_in, const int* in_sizes, int n_in,
                              void* d_out, int out_size, void* d_ws, size_t ws_size,
                              hipStream_t stream) {
    const float* x  = (const float*)d_in[0];
    const int* edges = (const int*)d_in[1];
    const float* W0 = (const float*)d_in[2];
    const float* b0 = (const float*)d_in[3];
    const float* Wh = (const float*)d_in[4];
    const float* ah = (const float*)d_in[5];
    const float* We = (const float*)d_in[6];
    const float* ae = (const float*)d_in[7];
    float* dout = (float*)d_out;

    const int Nn = in_sizes[0] / 128;   // 100000
    const int E  = in_sizes[1] / 2;     // 1600000
    const int* src = edges;
    const int* dst = edges + E;
    const int npo = (Nn + 7) / 8;       // nodes per XCD owner

    char* p = (char*)d_ws;
    auto alloc = [&](size_t bytes) -> char* {
        char* r = p;
        p += (bytes + 255) & ~(size_t)255;
        return r;
    };
    unsigned short* W0t   = (unsigned short*)alloc(128 * 128 * 2);
    unsigned short* Ballt = (unsigned short*)alloc(512 * 128 * 2);
    unsigned short* Wendt = (unsigned short*)alloc((size_t)64 * 512 * 2);
    unsigned short* Bscore = (unsigned short*)alloc(16 * 128 * 2);
    int* deg     = (int*)alloc((size_t)Nn * 4);
    int* incl    = (int*)alloc((size_t)Nn * 4);
    int* part    = (int*)alloc(512 * 4);
    int* row_ptr = (int*)alloc((size_t)(Nn + 1) * 4);
    int* cursor  = (int*)alloc((size_t)Nn * 4);
    int* dstp    = (int*)alloc((size_t)E * 4);
    float* s16   = (float*)alloc((size_t)Nn * 16 * 4);
    float* ss2   = (float*)alloc((size_t)Nn * 4);
    float* sd2   = (float*)alloc((size_t)Nn * 4);
    unsigned short* xp = (unsigned short*)alloc((size_t)Nn * 128 * 2);
    unsigned short* z  = (unsigned short*)alloc((size_t)CHUNK * 1024 * 2); // h2b aliases
    unsigned short* hcat = (unsigned short*)alloc((size_t)Nn * 512 * 2);
    unsigned short* h2b = (unsigned short*)z;   // [N,64] bf16 = 12.8 MB << z

    size_t needed = (size_t)(p - (char*)d_ws);
    if (needed > ws_size) return;       // diagnostic guard

    const int gm = (Nn + 127) / 128;
    const int nScanB = (Nn + SCAN_BS - 1) / SCAN_BS;
    const int eb = (E + 255) / 256;     // edge chunks

    hipMemsetAsync(deg, 0, (size_t)Nn * 4, stream);
    pack_all<<<452, 256, 0, stream>>>(W0, Wh, We, ah, W0t, Ballt, Wendt, Bscore);

    edge_hist_own<<<eb * 8, 256, 0, stream>>>(src, deg, E, npo);
    scan_blocks<<<nScanB, 256, 0, stream>>>(deg, incl, part, Nn);
    scan_partials<<<1, 512, 0, stream>>>(part, nScanB);
    finalize_rowptr<<<(Nn + 256) / 256, 256, 0, stream>>>(deg, incl, part, row_ptr, cursor, Nn, E);
    edge_scatter_own<<<eb * 8, 256, 0, stream>>>(src, dst, cursor, dstp, E, npo);

    // xp = bf16(x @ W0 + b0)
    gemm_mfma<128, 128, 128, 2, 2, 4, 4, true, true, true, false, false>
        <<<dim3(gm, 1), 256, 0, stream>>>(x, W0t, b0, xp, Nn, 128, 128);

    // s16[N,16] = xp @ Bscore^T  (cols 0..7 = src scores, 8..15 = dst scores)
    gemm_mfma<128, 16, 128, 4, 1, 2, 1, false, false, false, false, false>
        <<<dim3(gm, 1), 256, 0, stream>>>(xp, Bscore, nullptr, s16, Nn, 128, 16);

    // chunked: z = normalized xp-aggregation; hcat = ELU(z_h @ W_h) per head
    for (int c0 = 0; c0 < Nn; c0 += CHUNK) {
        int c1 = min(c0 + CHUNK, Nn);
        int Mc = c1 - c0;
        agg_xp<<<(Mc + 1) / 2, 256, 0, stream>>>(row_ptr, dstp, s16, xp, z, c0, c1);
        gemm_mfma<128, 64, 128, 4, 1, 2, 4, false, false, true, true, true>
            <<<dim3((Mc + 127) / 128, 1, 8), 256, 0, stream>>>(
                z, Ballt, nullptr, hcat + (size_t)c0 * 512, Mc, 1024, 512);
    }

    // h2b = bf16(hcat @ W_end)  [N,64]   (aliases z, now dead)
    gemm_mfma<128, 64, 512, 4, 1, 2, 4, false, false, true, false, false>
        <<<dim3(gm, 1), 256, 0, stream>>>(hcat, Wendt, nullptr, h2b, Nn, 512, 64);

    scores2<<<(Nn + 3) / 4, 256, 0, stream>>>(h2b, ae, ss2, sd2, Nn);
    agg_final<<<(Nn + 3) / 4, 256, 0, stream>>>(row_ptr, dstp, ss2, sd2, h2b, dout, Nn);
}